// Round 8
// baseline (453.295 us; speedup 1.0000x reference)
//
#include <hip/hip_runtime.h>
#include <hip/hip_bf16.h>

typedef __bf16 bf16;
typedef __attribute__((ext_vector_type(4)))  __bf16 bf16x4;
typedef __attribute__((ext_vector_type(8)))  __bf16 bf16x8;
typedef __attribute__((ext_vector_type(16))) float  f32x16;

#define B_   512
#define NC_  512
#define K_   4
#define S_   8
#define H_   128
#define D_   64
#define XROW (NC_ * K_)

#define SEGS 2
#define ITEMS_PER_BLOCK (B_ / SEGS)   // 256; per wave 64 items -> 8 iters
#define NITER 8

// pi: swap bits 2,3 of within-32 index (involution). Hidden dims stored
// physically permuted so the 32x32 MFMA C/D register layout of layer k IS
// the B-fragment layout of layer k+1 (r3/r6-verified algebra).
static __device__ __forceinline__ int swap23(int v) {
    return (v & ~12) | ((v & 4) << 1) | ((v & 8) >> 1);
}

// launch_bounds(256,3): allocator budget 512/3=170 VGPRs. Steady-state demand
// ~155 (Cc 64 + hf 32 + w2b 16 + misc) -> no spill (verify WRITE_SIZE!),
// 3 waves/SIMD + 50KB LDS -> 3 blocks/CU. r6's failure was w2r+A+hf+Cc
// (~230 demand) under a 128 cap; r7 proved weights-in-regs kills TLP.
__global__ __launch_bounds__(256, 3)
void jt_mlp_kernel(const int*   __restrict__ x,
                   const float* __restrict__ W1g, const float* __restrict__ b1g,
                   const float* __restrict__ W2g, const float* __restrict__ b2g,
                   const float* __restrict__ W3g, const float* __restrict__ b3g,
                   float* __restrict__ out)
{
    // Swizzled bf16 weight stores: element (p,k) lives at
    //   row p * rowlen + ((k>>3) ^ (p & chmask)) * 8 + (k&7)
    // -> every wave64 b128 fragment read is bank-uniform (conflict-free).
    __shared__ __align__(16) bf16 SW1[128 * 64];    // 16 KB  W1^T (b1 folded)
    __shared__ __align__(16) bf16 SW2[128 * 128];   // 32 KB  W2^T
    __shared__ __align__(16) bf16 SW3[8 * 128];     // 2 KB   W3^T

    const int tid  = threadIdx.x;
    const int lane = tid & 63;
    const int w    = tid >> 6;      // wave 0..3: items [seg*256 + w*64, +64)
    const int l31  = lane & 31;
    const int lhi  = lane >> 5;
    const int kk   = l31 & 3;
    const int n    = blockIdx.x >> 1;   // clique
    const int seg  = blockIdx.x & 1;

    const float* W1p = W1g + (size_t)n * (D_ * H_);
    const float* W2p = W2g + (size_t)n * (H_ * H_);
    const float* W3p = W3g + (size_t)n * (H_ * S_);
    const float* b1p = b1g + n * H_;
    const float* b2p = b2g + n * H_;
    const float* b3p = b3g + n * S_;

    const int p31 = swap23(l31);
    const bf16 one = (bf16)1.0f, zero = (bf16)0.0f;

    // ================= stage weights into LDS (coalesced float4) =================
    // W1: physical row p holds W1[k][pi(p)]; k<8 rows carry +b1 (parent-var-0
    // one-hot fires it exactly once; root n==0 zeroes k<32 except the bias).
    {
        const int c0 = (tid & 31) * 4;
        const int k0 = (tid >> 5) * 8;          // 0..56
        float rows[8][4];
#pragma unroll
        for (int i = 0; i < 8; ++i) {
            float4 t4 = *(const float4*)(W1p + (k0 + i) * H_ + c0);
            if (n == 0 && k0 < 32) t4 = make_float4(0.f, 0.f, 0.f, 0.f);
            rows[i][0] = t4.x; rows[i][1] = t4.y; rows[i][2] = t4.z; rows[i][3] = t4.w;
        }
        if (k0 == 0) {
            const float4 bb = *(const float4*)(b1p + c0);
#pragma unroll
            for (int i = 0; i < 8; ++i) {
                rows[i][0] += bb.x; rows[i][1] += bb.y;
                rows[i][2] += bb.z; rows[i][3] += bb.w;
            }
        }
#pragma unroll
        for (int j2 = 0; j2 < 4; ++j2) {
            const int c = c0 + j2;
            const int p = (c & ~31) | swap23(c & 31);
            const int ch = (k0 >> 3) ^ (p & 7);
            bf16x4 lo, hi;
#pragma unroll
            for (int i = 0; i < 4; ++i) {
                lo[i] = (bf16)rows[i][j2];
                hi[i] = (bf16)rows[4 + i][j2];
            }
            *(bf16x4*)&SW1[p * 64 + ch * 8 + 0] = lo;
            *(bf16x4*)&SW1[p * 64 + ch * 8 + 4] = hi;
        }
    }
    // W2
    {
        const int c0 = (tid & 31) * 4;
        const int kbase = (tid >> 5) * 16;      // 0..112
#pragma unroll
        for (int hh = 0; hh < 2; ++hh) {
            const int k0 = kbase + hh * 8;
            float rows[8][4];
#pragma unroll
            for (int i = 0; i < 8; ++i) {
                const float4 t4 = *(const float4*)(W2p + (k0 + i) * H_ + c0);
                rows[i][0] = t4.x; rows[i][1] = t4.y; rows[i][2] = t4.z; rows[i][3] = t4.w;
            }
#pragma unroll
            for (int j2 = 0; j2 < 4; ++j2) {
                const int c = c0 + j2;
                const int p = (c & ~31) | swap23(c & 31);
                const int ch = (k0 >> 3) ^ (p & 15);
                bf16x4 lo, hi;
#pragma unroll
                for (int i = 0; i < 4; ++i) {
                    lo[i] = (bf16)rows[i][j2];
                    hi[i] = (bf16)rows[4 + i][j2];
                }
                *(bf16x4*)&SW2[p * 128 + ch * 8 + 0] = lo;
                *(bf16x4*)&SW2[p * 128 + ch * 8 + 4] = hi;
            }
        }
    }
    // W3^T[s][k] (states not permuted; k logical)
    if (tid < 128) {
        const int s = tid >> 4, kc = tid & 15, k0 = kc * 8;
        float vv[8];
#pragma unroll
        for (int i = 0; i < 8; ++i) vv[i] = W3p[(k0 + i) * S_ + s];
        const int ch = kc ^ s;
        bf16x4 lo, hi;
#pragma unroll
        for (int i = 0; i < 4; ++i) { lo[i] = (bf16)vv[i]; hi[i] = (bf16)vv[4 + i]; }
        *(bf16x4*)&SW3[s * 128 + ch * 8 + 0] = lo;
        *(bf16x4*)&SW3[s * 128 + ch * 8 + 4] = hi;
    }

    // ---- small per-wave invariants ----
    bf16x8 w2b[4];          // b2 as k=0-slot bias fragments (fired by onef)
#pragma unroll
    for (int a = 0; a < 4; ++a) {
#pragma unroll
        for (int j = 0; j < 8; ++j) w2b[a][j] = zero;
        w2b[a][0] = lhi ? zero : (bf16)b2p[32 * a + p31];
    }
    bf16x8 onef;
#pragma unroll
    for (int j = 0; j < 8; ++j) onef[j] = zero;
    onef[0] = lhi ? zero : one;
    const float4 b3q = *(const float4*)(b3p + 4 * lhi);   // states 4lhi..4lhi+3

    f32x16 zf;
#pragma unroll
    for (int i = 0; i < 16; ++i) zf[i] = 0.f;

    __syncthreads();   // the ONLY barrier — weights visible; waves free-run now

    // -------- x prefetch --------
    const int itbase = seg * ITEMS_PER_BLOCK + w * 64 + (l31 >> 2);
    int4 xo_c, xp_c;
    {
        const int* xb = x + (size_t)itbase * XROW + n * K_;
        xo_c = *(const int4*)xb;
        xp_c = (n > 0) ? *(const int4*)(xb - K_) : make_int4(0, 0, 0, 0);
    }

#pragma unroll 1
    for (int c = 0; c < NITER; ++c) {
        const int item = itbase + c * 8;
        const int4 xo = xo_c, xp = xp_c;
        if (c < NITER - 1) {
            const int* xb = x + (size_t)(item + 8) * XROW + n * K_;
            xo_c = *(const int4*)xb;
            xp_c = (n > 0) ? *(const int4*)(xb - K_) : make_int4(0, 0, 0, 0);
        }

        // ---- one-hot B-frags from x (r3-verified) ----
        int sel[4];
        sel[0] = (n > 0) ? (lhi ? xp.y : xp.x) : (lhi ? -1 : 0);
        sel[1] = (n > 0) ? (lhi ? xp.w : xp.z) : -1;
        sel[2] = (kk > (lhi ? 1 : 0)) ? (lhi ? xo.y : xo.x) : -1;
        sel[3] = (kk > (lhi ? 3 : 2)) ? (lhi ? xo.w : xo.z) : -1;
        bf16x8 bf1[4];
#pragma unroll
        for (int kt = 0; kt < 4; ++kt)
#pragma unroll
            for (int j = 0; j < 8; ++j)
                bf1[kt][j] = (sel[kt] == j) ? one : zero;

        // ---- layer 1: weights streamed from LDS (conflict-free b128) ----
        f32x16 A[4];
#pragma unroll
        for (int a = 0; a < 4; ++a) A[a] = zf;
#pragma unroll
        for (int kt = 0; kt < 4; ++kt)
#pragma unroll
            for (int a = 0; a < 4; ++a) {
                const bf16x8 f = *(const bf16x8*)
                    &SW1[(32 * a + l31) * 64 + (((kt << 1) + lhi) ^ (l31 & 7)) * 8];
                A[a] = __builtin_amdgcn_mfma_f32_32x32x16_bf16(f, bf1[kt], A[a], 0, 0, 0);
            }

        // ---- extract h1 B-frags in-register (chained layout), A dies ----
        bf16x8 hf[8];
#pragma unroll
        for (int t = 0; t < 8; ++t)
#pragma unroll
            for (int j = 0; j < 8; ++j)
                hf[t][j] = (bf16)fmaxf(A[t >> 1][8 * (t & 1) + j], 0.f);

        // ---- layer 2: ALL kt from LDS (no register W2 cache — r6 lesson) ----
        f32x16 Cc[4];
#pragma unroll
        for (int a = 0; a < 4; ++a) Cc[a] = zf;
#pragma unroll
        for (int t = 0; t < 8; ++t)
#pragma unroll
            for (int a = 0; a < 4; ++a) {
                const int p = 32 * a + l31;
                const bf16x8 f = *(const bf16x8*)
                    &SW2[p * 128 + (((t << 1) + lhi) ^ (l31 & 15)) * 8];
                Cc[a] = __builtin_amdgcn_mfma_f32_32x32x16_bf16(f, hf[t], Cc[a], 0, 0, 0);
            }
#pragma unroll
        for (int a = 0; a < 4; ++a)
            Cc[a] = __builtin_amdgcn_mfma_f32_32x32x16_bf16(w2b[a], onef, Cc[a], 0, 0, 0);

        // ---- extract h2 B-frags, Cc dies ----
        bf16x8 hg[8];
#pragma unroll
        for (int t = 0; t < 8; ++t)
#pragma unroll
            for (int j = 0; j < 8; ++j)
                hg[t][j] = (bf16)fmaxf(Cc[t >> 1][8 * (t & 1) + j], 0.f);

        // ---- layer 3: full k in-wave; rows m=0..7 = states ----
        f32x16 L = zf;
#pragma unroll
        for (int t = 0; t < 8; ++t) {
            const int s2 = l31 & 7;   // lanes 8..31 duplicate rows (outputs unused)
            const bf16x8 f = *(const bf16x8*)
                &SW3[s2 * 128 + (((t << 1) + lhi) ^ s2) * 8];
            L = __builtin_amdgcn_mfma_f32_32x32x16_bf16(f, hg[t], L, 0, 0, 0);
        }
        // D: col = l31 = batch row; regs 0..3 = states 4*lhi..4*lhi+3

        // ---- register log-softmax + gather + sum over K (r3-verified) ----
        const float Ls0 = L[0] + b3q.x, Ls1 = L[1] + b3q.y;
        const float Ls2 = L[2] + b3q.z, Ls3 = L[3] + b3q.w;
        float m4 = fmaxf(fmaxf(Ls0, Ls1), fmaxf(Ls2, Ls3));
        const float mm = fmaxf(m4, __shfl_xor(m4, 32));
        float e = __expf(Ls0 - mm) + __expf(Ls1 - mm) +
                  __expf(Ls2 - mm) + __expf(Ls3 - mm);
        const float ssum = e + __shfl_xor(e, 32);
        const int xs = (kk & 2) ? ((kk & 1) ? xo.w : xo.z)
                                : ((kk & 1) ? xo.y : xo.x);
        const float own = (xs & 2) ? ((xs & 1) ? Ls3 : Ls2)
                                   : ((xs & 1) ? Ls1 : Ls0);
        const float oth = __shfl_xor(own, 32);
        const float obs = ((xs >> 2) == lhi) ? own : oth;
        float lp = obs - mm - __logf(ssum);
        lp += __shfl_xor(lp, 1);
        lp += __shfl_xor(lp, 2);
        if (lhi == 0 && kk == 0)
            out[(size_t)item * NC_ + n] = lp;
    }
}

extern "C" void kernel_launch(void* const* d_in, const int* in_sizes, int n_in,
                              void* d_out, int out_size, void* d_ws, size_t ws_size,
                              hipStream_t stream) {
    const int*   x  = (const int*)d_in[0];
    const float* W1 = (const float*)d_in[1];
    const float* b1 = (const float*)d_in[2];
    const float* W2 = (const float*)d_in[3];
    const float* b2 = (const float*)d_in[4];
    const float* W3 = (const float*)d_in[5];
    const float* b3 = (const float*)d_in[6];
    float* out = (float*)d_out;
    jt_mlp_kernel<<<dim3(NC_ * SEGS), 256, 0, stream>>>(x, W1, b1, W2, b2, W3, b3, out);
}

// Round 9
// 168.035 us; speedup vs baseline: 2.6976x; 2.6976x over previous
//
#include <hip/hip_runtime.h>
#include <hip/hip_bf16.h>

typedef __bf16 bf16;
typedef __attribute__((ext_vector_type(4)))  __bf16 bf16x4;
typedef __attribute__((ext_vector_type(8)))  __bf16 bf16x8;
typedef __attribute__((ext_vector_type(16))) float  f32x16;

#define B_   512
#define NC_  512
#define K_   4
#define S_   8
#define H_   128
#define D_   64
#define XROW (NC_ * K_)
#define NITER 32        // 512 items / (2 pairs * 8 items/iter)

// pi: swap bits 2,3 of within-32 index (involution). Hidden dims stored
// physically permuted so the 32x32 MFMA C/D register layout of layer k IS
// the B-fragment layout of layer k+1 (r3/r5/r8-verified algebra).
static __device__ __forceinline__ int swap23(int v) {
    return (v & ~12) | ((v & 4) << 1) | ((v & 8) >> 1);
}

// (256,2): empirical allocator law (r3..r8): VGPR budget = 256/min_waves.
// Steady-state VGPR demand here ~113 (w1f 32 + hfo 16 + addr/x/misc) since
// accumulators (A/Cc/L ~80) go to AGPRs and W2/W3 stream from LDS.
__global__ __launch_bounds__(256, 2)
void jt_mlp_kernel(const int*   __restrict__ x,
                   const float* __restrict__ W1g, const float* __restrict__ b1g,
                   const float* __restrict__ W2g, const float* __restrict__ b2g,
                   const float* __restrict__ W3g, const float* __restrict__ b3g,
                   float* __restrict__ out)
{
    // Swizzled weights: element (row p, k) at p*rowlen + ch*8 + (k&7),
    //   W1: ch = (k>>3) ^ (p&7)
    //   W2: ch = (k>>3) ^ (p&15) ^ ((p&16)>>2)   (5th bit: kills the
    //       l31 vs l31+16 same-bank alias -> 8-access/bank minimum)
    __shared__ __align__(16) bf16 SW2[128 * 128];   // 32 KB
    __shared__ __align__(16) bf16 SWX[128 * 64];    // 16 KB: W1 staging, then HX
    __shared__ __align__(16) bf16 SW3[8 * 128];     // 2 KB
    __shared__ __align__(16) float LX[2][64][4];    // 2 KB (h=1 writes, h=0 reads)

    const int tid  = threadIdx.x;
    const int lane = tid & 63;
    const int w    = tid >> 6;      // 0..3
    const int pair = w >> 1;        // 0,1
    const int h    = w & 1;         // H-half owned by this wave
    const int l31  = lane & 31;
    const int lhi  = lane >> 5;
    const int kk   = l31 & 3;
    const int n    = blockIdx.x;    // clique (512 blocks, SEGS=1)

    const float* W1p = W1g + (size_t)n * (D_ * H_);
    const float* W2p = W2g + (size_t)n * (H_ * H_);
    const float* W3p = W3g + (size_t)n * (H_ * S_);
    const float* b1p = b1g + n * H_;
    const float* b2p = b2g + n * H_;
    const float* b3p = b3g + n * S_;

    const int p31 = swap23(l31);
    const bf16 one = (bf16)1.0f, zero = (bf16)0.0f;

    // ============ stage weights into LDS (coalesced float4; r8-proven) ============
    // W1 -> SWX (temporarily). k<8 rows carry +b1; root n==0 zeroes k<32 first.
    {
        const int c0 = (tid & 31) * 4;
        const int k0 = (tid >> 5) * 8;          // 0..56
        float rows[8][4];
#pragma unroll
        for (int i = 0; i < 8; ++i) {
            float4 t4 = *(const float4*)(W1p + (k0 + i) * H_ + c0);
            if (n == 0 && k0 < 32) t4 = make_float4(0.f, 0.f, 0.f, 0.f);
            rows[i][0] = t4.x; rows[i][1] = t4.y; rows[i][2] = t4.z; rows[i][3] = t4.w;
        }
        if (k0 == 0) {
            const float4 bb = *(const float4*)(b1p + c0);
#pragma unroll
            for (int i = 0; i < 8; ++i) {
                rows[i][0] += bb.x; rows[i][1] += bb.y;
                rows[i][2] += bb.z; rows[i][3] += bb.w;
            }
        }
#pragma unroll
        for (int j2 = 0; j2 < 4; ++j2) {
            const int c = c0 + j2;
            const int p = (c & ~31) | swap23(c & 31);
            const int ch = (k0 >> 3) ^ (p & 7);
            bf16x4 lo, hi;
#pragma unroll
            for (int i = 0; i < 4; ++i) {
                lo[i] = (bf16)rows[i][j2];
                hi[i] = (bf16)rows[4 + i][j2];
            }
            *(bf16x4*)&SWX[p * 64 + ch * 8 + 0] = lo;
            *(bf16x4*)&SWX[p * 64 + ch * 8 + 4] = hi;
        }
    }
    // W2 -> SW2 (5-bit swizzle)
    {
        const int c0 = (tid & 31) * 4;
        const int kbase = (tid >> 5) * 16;      // 0..112
#pragma unroll
        for (int hh = 0; hh < 2; ++hh) {
            const int k0 = kbase + hh * 8;
            float rows[8][4];
#pragma unroll
            for (int i = 0; i < 8; ++i) {
                const float4 t4 = *(const float4*)(W2p + (k0 + i) * H_ + c0);
                rows[i][0] = t4.x; rows[i][1] = t4.y; rows[i][2] = t4.z; rows[i][3] = t4.w;
            }
#pragma unroll
            for (int j2 = 0; j2 < 4; ++j2) {
                const int c = c0 + j2;
                const int p = (c & ~31) | swap23(c & 31);
                const int ch = (k0 >> 3) ^ (p & 15) ^ ((p & 16) >> 2);
                bf16x4 lo, hi;
#pragma unroll
                for (int i = 0; i < 4; ++i) {
                    lo[i] = (bf16)rows[i][j2];
                    hi[i] = (bf16)rows[4 + i][j2];
                }
                *(bf16x4*)&SW2[p * 128 + ch * 8 + 0] = lo;
                *(bf16x4*)&SW2[p * 128 + ch * 8 + 4] = hi;
            }
        }
    }
    // W3^T[s][k] -> SW3
    if (tid < 128) {
        const int s = tid >> 4, kc = tid & 15, k0 = kc * 8;
        float vv[8];
#pragma unroll
        for (int i = 0; i < 8; ++i) vv[i] = W3p[(k0 + i) * S_ + s];
        const int ch = kc ^ s;
        bf16x4 lo, hi;
#pragma unroll
        for (int i = 0; i < 4; ++i) { lo[i] = (bf16)vv[i]; hi[i] = (bf16)vv[4 + i]; }
        *(bf16x4*)&SW3[s * 128 + ch * 8 + 0] = lo;
        *(bf16x4*)&SW3[s * 128 + ch * 8 + 4] = hi;
    }
    __syncthreads();

    // ---- W1 fragments for this wave's H-half: registers, from LDS ----
    bf16x8 w1f[2][4];
#pragma unroll
    for (int aa = 0; aa < 2; ++aa)
#pragma unroll
        for (int kt = 0; kt < 4; ++kt)
            w1f[aa][kt] = *(const bf16x8*)
                &SWX[(32 * (2 * h + aa) + l31) * 64 + (((kt << 1) + lhi) ^ (l31 & 7)) * 8];
    // ---- W3 fragments (this wave's k-half: kglobal = 64h+16tt+8lhi+j) ----
    const int s2 = l31 & 7;   // lanes 8..31 duplicate state rows (outputs unused)
    bf16x8 w3f[4];
#pragma unroll
    for (int tt = 0; tt < 4; ++tt)
        w3f[tt] = *(const bf16x8*)
            &SW3[s2 * 128 + ((((4 * h + tt) << 1) + lhi) ^ s2) * 8];
    // ---- bias frags ----
    bf16x8 w2b0, w2b1, onef;
#pragma unroll
    for (int j = 0; j < 8; ++j) { w2b0[j] = zero; w2b1[j] = zero; onef[j] = zero; }
    w2b0[0] = lhi ? zero : (bf16)b2p[32 * (2 * h + 0) + p31];
    w2b1[0] = lhi ? zero : (bf16)b2p[32 * (2 * h + 1) + p31];
    onef[0] = lhi ? zero : one;
    const float4 b3q = *(const float4*)(b3p + 4 * lhi);

    f32x16 zf;
#pragma unroll
    for (int i = 0; i < 16; ++i) zf[i] = 0.f;

    __syncthreads();   // w1f reads done -> SWX becomes the HX exchange buffer
    bf16* HX = SWX;    // HX[pair][half][t][lane][8] = ((pair*2+half)*4+t)*512 + lane*8

    // -------- x prefetch --------
    const int itbase = pair * 256 + (l31 >> 2);
    int4 xo_c, xp_c;
    {
        const int* xb = x + (size_t)itbase * XROW + n * K_;
        xo_c = *(const int4*)xb;
        xp_c = (n > 0) ? *(const int4*)(xb - K_) : make_int4(0, 0, 0, 0);
    }

#pragma unroll 1
    for (int c = 0; c < NITER; ++c) {
        const int item = itbase + c * 8;
        const int4 xo = xo_c, xp = xp_c;
        if (c < NITER - 1) {
            const int* xb = x + (size_t)(item + 8) * XROW + n * K_;
            xo_c = *(const int4*)xb;
            xp_c = (n > 0) ? *(const int4*)(xb - K_) : make_int4(0, 0, 0, 0);
        }

        // ---- one-hot selectors (r3/r5-proven) ----
        int sel[4];
        sel[0] = (n > 0) ? (lhi ? xp.y : xp.x) : (lhi ? -1 : 0);
        sel[1] = (n > 0) ? (lhi ? xp.w : xp.z) : -1;
        sel[2] = (kk > (lhi ? 1 : 0)) ? (lhi ? xo.y : xo.x) : -1;
        sel[3] = (kk > (lhi ? 3 : 2)) ? (lhi ? xo.w : xo.z) : -1;

        // ---- layer 1 (own H-half; one-hot B-frag built per kt) ----
        f32x16 A0 = zf, A1 = zf;
#pragma unroll
        for (int kt = 0; kt < 4; ++kt) {
            bf16x8 bf1;
#pragma unroll
            for (int j = 0; j < 8; ++j) bf1[j] = (sel[kt] == j) ? one : zero;
            A0 = __builtin_amdgcn_mfma_f32_32x32x16_bf16(w1f[0][kt], bf1, A0, 0, 0, 0);
            A1 = __builtin_amdgcn_mfma_f32_32x32x16_bf16(w1f[1][kt], bf1, A1, 0, 0, 0);
        }

        // ---- extract own h1 frags (chained layout), publish to partner ----
        bf16x8 hfo[4];
#pragma unroll
        for (int t = 0; t < 4; ++t) {
            const f32x16& S = (t < 2) ? A0 : A1;
#pragma unroll
            for (int j = 0; j < 8; ++j)
                hfo[t][j] = (bf16)fmaxf(S[8 * (t & 1) + j], 0.f);
            *(bf16x8*)&HX[(((pair << 1) + h) * 4 + t) * 512 + lane * 8] = hfo[t];
        }
        __syncthreads();

        // ---- layer 2: W2 frags streamed from LDS; own kt then partner kt ----
        f32x16 C0 = zf, C1 = zf;
        const int swz = (l31 & 15) ^ ((l31 & 16) >> 2);
        const int p0 = (64 * h + l31) * 128;
        const int p1 = (64 * h + 32 + l31) * 128;
#pragma unroll
        for (int tt = 0; tt < 4; ++tt) {
            const int chunk = (((4 * h + tt) << 1) + lhi) ^ swz;
            const bf16x8 f0 = *(const bf16x8*)&SW2[p0 + chunk * 8];
            const bf16x8 f1 = *(const bf16x8*)&SW2[p1 + chunk * 8];
            C0 = __builtin_amdgcn_mfma_f32_32x32x16_bf16(f0, hfo[tt], C0, 0, 0, 0);
            C1 = __builtin_amdgcn_mfma_f32_32x32x16_bf16(f1, hfo[tt], C1, 0, 0, 0);
        }
#pragma unroll
        for (int tt = 0; tt < 4; ++tt) {
            const bf16x8 hp = *(const bf16x8*)
                &HX[(((pair << 1) + (1 - h)) * 4 + tt) * 512 + lane * 8];
            const int chunk = (((4 * (1 - h) + tt) << 1) + lhi) ^ swz;
            const bf16x8 f0 = *(const bf16x8*)&SW2[p0 + chunk * 8];
            const bf16x8 f1 = *(const bf16x8*)&SW2[p1 + chunk * 8];
            C0 = __builtin_amdgcn_mfma_f32_32x32x16_bf16(f0, hp, C0, 0, 0, 0);
            C1 = __builtin_amdgcn_mfma_f32_32x32x16_bf16(f1, hp, C1, 0, 0, 0);
        }
        C0 = __builtin_amdgcn_mfma_f32_32x32x16_bf16(w2b0, onef, C0, 0, 0, 0);
        C1 = __builtin_amdgcn_mfma_f32_32x32x16_bf16(w2b1, onef, C1, 0, 0, 0);

        // ---- layer 3 partial over own k-half ----
        f32x16 L = zf;
#pragma unroll
        for (int tt = 0; tt < 4; ++tt) {
            bf16x8 hg;
            const f32x16& S = (tt < 2) ? C0 : C1;
#pragma unroll
            for (int j = 0; j < 8; ++j)
                hg[j] = (bf16)fmaxf(S[8 * (tt & 1) + j], 0.f);
            L = __builtin_amdgcn_mfma_f32_32x32x16_bf16(w3f[tt], hg, L, 0, 0, 0);
        }

        // ---- sum partials across the pair; epilogue on h==0 (r5-proven) ----
        if (h == 1)
            *(float4*)&LX[pair][lane][0] = make_float4(L[0], L[1], L[2], L[3]);
        __syncthreads();
        if (h == 0) {
            const float4 Lp = *(const float4*)&LX[pair][lane][0];
            float Ls0 = L[0] + Lp.x + b3q.x;
            float Ls1 = L[1] + Lp.y + b3q.y;
            float Ls2 = L[2] + Lp.z + b3q.z;
            float Ls3 = L[3] + Lp.w + b3q.w;

            float m4 = fmaxf(fmaxf(Ls0, Ls1), fmaxf(Ls2, Ls3));
            const float mm = fmaxf(m4, __shfl_xor(m4, 32));
            float e = __expf(Ls0 - mm) + __expf(Ls1 - mm) +
                      __expf(Ls2 - mm) + __expf(Ls3 - mm);
            const float ssum = e + __shfl_xor(e, 32);

            const int xs = (kk & 2) ? ((kk & 1) ? xo.w : xo.z)
                                    : ((kk & 1) ? xo.y : xo.x);
            const float own = (xs & 2) ? ((xs & 1) ? Ls3 : Ls2)
                                       : ((xs & 1) ? Ls1 : Ls0);
            const float oth = __shfl_xor(own, 32);
            const float obs = ((xs >> 2) == lhi) ? own : oth;
            float lp = obs - mm - __logf(ssum);
            lp += __shfl_xor(lp, 1);
            lp += __shfl_xor(lp, 2);
            if (lhi == 0 && kk == 0)
                out[(size_t)item * NC_ + n] = lp;
        }
        // HX overwrite next iter is safe: all HX reads completed before the
        // second barrier; LX read (h==0) completes before next first barrier.
    }
}

extern "C" void kernel_launch(void* const* d_in, const int* in_sizes, int n_in,
                              void* d_out, int out_size, void* d_ws, size_t ws_size,
                              hipStream_t stream) {
    const int*   x  = (const int*)d_in[0];
    const float* W1 = (const float*)d_in[1];
    const float* b1 = (const float*)d_in[2];
    const float* W2 = (const float*)d_in[3];
    const float* b2 = (const float*)d_in[4];
    const float* W3 = (const float*)d_in[5];
    const float* b3 = (const float*)d_in[6];
    float* out = (float*)d_out;
    jt_mlp_kernel<<<dim3(NC_), 256, 0, stream>>>(x, W1, b1, W2, b2, W3, b3, out);
}